// Round 3
// baseline (867.224 us; speedup 1.0000x reference)
//
#include <hip/hip_runtime.h>
#include <stdint.h>

// B=8192, N=17, C=512, H=8, HD=64  — full pipeline in f16 (inputs fp32)

typedef __attribute__((ext_vector_type(4))) float f32x4;
typedef _Float16 f16x8 __attribute__((ext_vector_type(8)));
typedef _Float16 f16x2 __attribute__((ext_vector_type(2)));

__device__ __forceinline__ unsigned short f2h(float f) {
  return __builtin_bit_cast(unsigned short, (_Float16)f);
}
__device__ __forceinline__ float h2f(unsigned short h) {
  return (float)__builtin_bit_cast(_Float16, h);
}
__device__ __forceinline__ float fdot2u(uint32_t a, uint32_t b, float c) {
#if __has_builtin(__builtin_amdgcn_fdot2)
  return __builtin_amdgcn_fdot2(__builtin_bit_cast(f16x2, a),
                                __builtin_bit_cast(f16x2, b), c, false);
#else
  f16x2 A = __builtin_bit_cast(f16x2, a), B = __builtin_bit_cast(f16x2, b);
  return c + (float)A[0] * (float)B[0] + (float)A[1] * (float)B[1];
#endif
}

#define GLOAD_LDS16(gptr, lptr)                                          \
  __builtin_amdgcn_global_load_lds(                                      \
      (__attribute__((address_space(1))) void*)(gptr),                   \
      (__attribute__((address_space(3))) void*)(lptr), 16, 0, 0)

__device__ __forceinline__ f32x4 mfma16(f16x8 a, f16x8 b, f32x4 c) {
  return __builtin_amdgcn_mfma_f32_16x16x32_f16(a, b, c, 0, 0, 0);
}

// ---------------- cast fp32 -> f16, 4 elems/thread ----------------
__global__ __launch_bounds__(256) void k_cvt(const float* __restrict__ in,
                                             unsigned short* __restrict__ out,
                                             long n4) {
  long i = (long)blockIdx.x * 256 + threadIdx.x;
  if (i >= n4) return;
  float4 a = reinterpret_cast<const float4*>(in)[i];
  ushort4 o;
  o.x = f2h(a.x); o.y = f2h(a.y); o.z = f2h(a.z); o.w = f2h(a.w);
  reinterpret_cast<ushort4*>(out)[i] = o;
}

// ---------- transpose-cast W[K][N] fp32 -> Wt[N][K] f16 ----------
__global__ __launch_bounds__(256) void k_cvt_t(const float* __restrict__ W,
                                               unsigned short* __restrict__ Wt,
                                               int K, int N) {
  int i = blockIdx.x * 256 + threadIdx.x;
  if (i >= K * N) return;
  int n = i / K, k = i - n * K;
  Wt[i] = f2h(W[(size_t)k * N + n]);
}

// ============ 256x256 8-phase GEMM (T2+T3+T4+T5), C = A*Bt^T + bias =======
// A [M][K] f16, Bt [N][K] f16. BM=BN=256, BK=64, 8 waves (2Mx4N), 512 thr.
// LDS: 2 tile-buffers x (A 256x64 + B 256x64) f16 = 128 KB, linear layout,
// XOR-swizzle carried by pre-swizzled global source + swizzled ds_read.
// Half-tile staging order per K-tile: [A0, A1, B0, B1]; lead = 7 half-tiles;
// vmcnt(6) per K-tile switch (3 half-tiles in flight), vmcnt(0) at drain.

#define MFMA_QUAD(M0, N0)                                                  \
  __builtin_amdgcn_s_setprio(1);                                           \
  _Pragma("unroll") for (int m_ = 0; m_ < 4; m_++) {                       \
    _Pragma("unroll") for (int n_ = 0; n_ < 2; n_++) {                     \
      acc[(M0) + m_][(N0) + n_] =                                          \
          mfma16(a[(M0) + m_][0], b[(N0) + n_][0], acc[(M0) + m_][(N0) + n_]); \
      acc[(M0) + m_][(N0) + n_] =                                          \
          mfma16(a[(M0) + m_][1], b[(N0) + n_][1], acc[(M0) + m_][(N0) + n_]); \
    }                                                                      \
  }                                                                        \
  __builtin_amdgcn_s_setprio(0);

#define READ_A_HALF(MH)                                                    \
  _Pragma("unroll") for (int m_ = 0; m_ < 4; m_++) {                       \
    a[(MH)*4 + m_][0] =                                                    \
        *(const f16x8*)(ldsA + ub + ((MH)*4 + m_) * 1024 + gx0);           \
    a[(MH)*4 + m_][1] =                                                    \
        *(const f16x8*)(ldsA + ub + ((MH)*4 + m_) * 1024 + gx1);           \
  }
#define READ_B_HALF(NH)                                                    \
  _Pragma("unroll") for (int n_ = 0; n_ < 2; n_++) {                       \
    b[(NH)*2 + n_][0] =                                                    \
        *(const f16x8*)(ldsB + ub + ((NH)*2 + n_) * 1024 + gx0);           \
    b[(NH)*2 + n_][1] =                                                    \
        *(const f16x8*)(ldsB + ub + ((NH)*2 + n_) * 1024 + gx1);           \
  }

template <int KT, bool F16OUT>
__global__ __launch_bounds__(512, 2) void k_gemm256(
    const unsigned short* __restrict__ A,   // [M][K] f16
    const unsigned short* __restrict__ Bt,  // [N][K] f16
    const float* __restrict__ bias,         // [N]
    void* __restrict__ Cout,                // [M][N] f16 or fp32
    int M, int N, int K) {
  __shared__ __align__(16) unsigned short lds[2][2][256 * 64];

  const int tid = threadIdx.x;
  const int w = tid >> 6, lane = tid & 63;
  const int wm = w >> 2, wn = w & 3;
  const int lr = lane & 15, lk = lane >> 4;

  // bijective XCD swizzle (grid % 8 == 0)
  const int bid = (blockIdx.x & 7) * ((int)gridDim.x >> 3) + (blockIdx.x >> 3);
  const int nbn = N >> 8;
  const int brow = (bid / nbn) << 8;
  const int bcol = (bid % nbn) << 8;

  // ---- staging source (pre-swizzled global col; LDS dest stays linear) ----
  const int srow = lane >> 3;                  // row within 8-row slab
  const int scol = (((lane & 7) ^ srow) << 3); // swizzled granule * 8 f16
  const unsigned short* pA = A + (size_t)(brow + (w << 3) + srow) * K + scol;
  const unsigned short* pB = Bt + (size_t)(bcol + (w << 3) + srow) * K + scol;

  // stage half-tile h: u'=h>>2, s=h&3 (0:A0 1:A1 2:B0 3:B1)
  auto STAGE = [&](int h) {
    const int uu = h >> 2, s = h & 3;
    const int isB = s >> 1, half = s & 1;
    const unsigned short* src =
        (isB ? pB : pA) + (size_t)(half * 128) * K + uu * 64;
    unsigned short* dst = &lds[uu & 1][isB][(half * 128 + (w << 3)) * 64];
    GLOAD_LDS16(src, dst);
    GLOAD_LDS16(src + (size_t)64 * K, dst + 64 * 64);
  };

  // ---- ds_read bases (swizzled granule = (kk*4+lk) ^ (lr&7)) ----
  const int gx0 = ((lk) ^ (lr & 7)) << 3;       // kk=0, in f16 units
  const int gx1 = ((4 + lk) ^ (lr & 7)) << 3;   // kk=1
  const unsigned short* ldsA = &lds[0][0][(wm * 128 + lr) * 64];
  const unsigned short* ldsB = &lds[0][1][(wn * 64 + lr) * 64];

  f32x4 acc[8][4];
#pragma unroll
  for (int m = 0; m < 8; m++)
#pragma unroll
    for (int n = 0; n < 4; n++) acc[m][n] = f32x4{0.f, 0.f, 0.f, 0.f};

  // ---- prologue: 7 half-tiles (tile0 complete + 3 of tile1) ----
#pragma unroll
  for (int h = 0; h < 7; ++h) STAGE(h);
  asm volatile("s_waitcnt vmcnt(6)" ::: "memory");
  __builtin_amdgcn_s_barrier();

  f16x8 a[8][2], b[4][2];
  for (int u = 0; u < KT; ++u) {
    const int ub = (u & 1) * 32768;  // buffer offset in shorts
    const int hbase = 4 * u + 7;
    // ---- ph0: reads m0-3 + n0-1 (12), MFMA (m0-3 x n0-1) ----
    READ_A_HALF(0)
    READ_B_HALF(0)
    if (hbase < 4 * KT) STAGE(hbase);
    __builtin_amdgcn_s_barrier();
    asm volatile("s_waitcnt lgkmcnt(0)" ::: "memory");
    __builtin_amdgcn_sched_barrier(0);
    MFMA_QUAD(0, 0)
    __builtin_amdgcn_s_barrier();
    // ---- ph1: reads m4-7 + n2-3 (12), MFMA (m0-3 x n2-3) ----
    READ_A_HALF(1)
    READ_B_HALF(1)
    if (hbase + 1 < 4 * KT) STAGE(hbase + 1);
    __builtin_amdgcn_s_barrier();
    asm volatile("s_waitcnt lgkmcnt(0)" ::: "memory");
    __builtin_amdgcn_sched_barrier(0);
    MFMA_QUAD(0, 2)
    __builtin_amdgcn_s_barrier();
    // ---- ph2: MFMA (m4-7 x n2-3) ----
    if (hbase + 2 < 4 * KT) STAGE(hbase + 2);
    __builtin_amdgcn_s_barrier();
    MFMA_QUAD(4, 2)
    __builtin_amdgcn_s_barrier();
    // ---- ph3: MFMA (m4-7 x n0-1) + K-tile-switch vmcnt ----
    if (hbase + 3 < 4 * KT) STAGE(hbase + 3);
    if (u + 2 < KT) {
      asm volatile("s_waitcnt vmcnt(6)" ::: "memory");
    } else if (u + 2 == KT) {
      asm volatile("s_waitcnt vmcnt(0)" ::: "memory");
    }
    __builtin_amdgcn_s_barrier();
    MFMA_QUAD(4, 0)
    __builtin_amdgcn_s_barrier();
  }

  // ---- epilogue: C/D layout col = lane&15, row = (lane>>4)*4 + r ----
  const int orow = brow + wm * 128 + (lane >> 4) * 4;
  const int ocol0 = bcol + wn * 64 + lr;
#pragma unroll
  for (int n = 0; n < 4; n++) {
    const int col = ocol0 + n * 16;
    const float bv = bias[col];
#pragma unroll
    for (int m = 0; m < 8; m++) {
      const int row = orow + m * 16;
#pragma unroll
      for (int r = 0; r < 4; r++) {
        float v = acc[m][n][r] + bv;
        if (F16OUT)
          ((unsigned short*)Cout)[(size_t)(row + r) * N + col] = f2h(v);
        else
          ((float*)Cout)[(size_t)(row + r) * N + col] = v;
      }
    }
  }
}

// ---------------- attention: one block per batch, wave-local phases -------
#define SQS4 129  // uint4 per padded row (1032 shorts = 516 words ≡ 4 mod 32)
__global__ __launch_bounds__(256) void k_attn(
    const unsigned short* __restrict__ qkv,  // [B*17][1536] f16
    const float* __restrict__ outer,         // [8][17][17]
    const float* __restrict__ alpha_p,       // [1]
    unsigned short* __restrict__ out) {      // [B*17][512] f16
  __shared__ __align__(16) uint4 sq4[17 * SQS4];
  __shared__ float sattn[4][17][18];
  __shared__ float sinv[4][17];

  const int b = blockIdx.x, tid = threadIdx.x;
  {
    const uint4* src = reinterpret_cast<const uint4*>(qkv + (size_t)b * 17 * 1536);
    for (int i = tid; i < 17 * 128; i += 256) {
      int row = i >> 7, seg = i & 127;
      sq4[row * SQS4 + seg] = src[row * 192 + seg];
    }
  }
  __syncthreads();

  const unsigned short* sq = (const unsigned short*)sq4;
  const float alpha = alpha_p[0];
  const int wid = tid >> 6, lane = tid & 63;

  for (int hh = 0; hh < 2; ++hh) {
    const int h = wid * 2 + hh;
    for (int p = lane; p < 289; p += 64) {
      const int r = p / 17, m = p - r * 17;
      const uint4* qr = reinterpret_cast<const uint4*>(sq + r * 1032 + h * 64);
      const uint4* km = reinterpret_cast<const uint4*>(sq + m * 1032 + 512 + h * 64);
      float acc = 0.f;
#pragma unroll
      for (int c = 0; c < 8; c++) {
        uint4 qa = qr[c], ka = km[c];
        acc = fdot2u(qa.x, ka.x, acc);
        acc = fdot2u(qa.y, ka.y, acc);
        acc = fdot2u(qa.z, ka.z, acc);
        acc = fdot2u(qa.w, ka.w, acc);
      }
      sattn[wid][r][m] = (acc + alpha * outer[h * 289 + p]) * 0.125f;
    }
    __builtin_amdgcn_wave_barrier();
    asm volatile("" ::: "memory");

    if (lane < 17) {
      float mx = -1e30f;
#pragma unroll
      for (int m = 0; m < 17; m++) mx = fmaxf(mx, sattn[wid][lane][m]);
      float s = 0.f;
#pragma unroll
      for (int m = 0; m < 17; m++) {
        float e = __expf(sattn[wid][lane][m] - mx);
        sattn[wid][lane][m] = e;
        s += e;
      }
      sinv[wid][lane] = 1.f / s;
    }
    __builtin_amdgcn_wave_barrier();
    asm volatile("" ::: "memory");

    float vr[17];
#pragma unroll
    for (int m = 0; m < 17; m++)
      vr[m] = h2f(qkv[((size_t)b * 17 + m) * 1536 + 1024 + h * 64 + lane]);
#pragma unroll 1
    for (int r = 0; r < 17; r++) {
      float acc = 0.f;
#pragma unroll
      for (int m = 0; m < 17; m++) acc += sattn[wid][r][m] * vr[m];
      out[((size_t)b * 17 + r) * 512 + h * 64 + lane] = f2h(acc * sinv[wid][r]);
    }
    __builtin_amdgcn_wave_barrier();
    asm volatile("" ::: "memory");
  }
}

// ---------------- launch ----------------
extern "C" void kernel_launch(void* const* d_in, const int* in_sizes, int n_in,
                              void* d_out, int out_size, void* d_ws,
                              size_t ws_size, hipStream_t stream) {
  const float* x      = (const float*)d_in[0];
  const float* W_qkv  = (const float*)d_in[1];
  const float* b_qkv  = (const float*)d_in[2];
  const float* outer  = (const float*)d_in[3];
  const float* alpha  = (const float*)d_in[4];
  const float* W_proj = (const float*)d_in[5];
  const float* b_proj = (const float*)d_in[6];

  char* ws = (char*)d_ws;
  unsigned short* xb  = (unsigned short*)(ws);              // 142,606,336 (reused as attn_out)
  unsigned short* qkv = (unsigned short*)(ws + 142606336);  // 427,819,008
  unsigned short* wqt = (unsigned short*)(ws + 570425344);  // 1,572,864
  unsigned short* wpt = (unsigned short*)(ws + 571998208);  // 524,288

  k_cvt<<<dim3(69632), dim3(256), 0, stream>>>(x, xb, 17825792L);
  k_cvt_t<<<dim3(3072), dim3(256), 0, stream>>>(W_qkv, wqt, 512, 1536);
  k_cvt_t<<<dim3(1024), dim3(256), 0, stream>>>(W_proj, wpt, 512, 512);
  // qkv GEMM: 544 row-tiles x 6 col-tiles = 3264 blocks (3264 % 8 == 0)
  k_gemm256<8, true><<<dim3(3264), dim3(512), 0, stream>>>(
      xb, wqt, b_qkv, qkv, 139264, 1536, 512);
  k_attn<<<dim3(8192), dim3(256), 0, stream>>>(qkv, outer, alpha, xb);
  // proj GEMM: 544 x 2 = 1088 blocks (1088 % 8 == 0), fp32 out
  k_gemm256<8, false><<<dim3(1088), dim3(512), 0, stream>>>(
      xb, wpt, b_proj, (float*)d_out, 139264, 512, 512);
}

// Round 4
// 726.487 us; speedup vs baseline: 1.1937x; 1.1937x over previous
//
#include <hip/hip_runtime.h>
#include <stdint.h>

// B=8192, N=17, C=512, H=8, HD=64 — f16 pipeline (inputs fp32)
// Fused: qkv-GEMM (head-grouped W) + per-batch attention in-epilogue.

typedef __attribute__((ext_vector_type(4))) float f32x4;
typedef _Float16 f16x8 __attribute__((ext_vector_type(8)));
typedef _Float16 f16x2 __attribute__((ext_vector_type(2)));

__device__ __forceinline__ unsigned short f2h(float f) {
  return __builtin_bit_cast(unsigned short, (_Float16)f);
}
__device__ __forceinline__ float h2f(unsigned short h) {
  return (float)__builtin_bit_cast(_Float16, h);
}
__device__ __forceinline__ float fdot2u(uint32_t a, uint32_t b, float c) {
  return __builtin_amdgcn_fdot2(__builtin_bit_cast(f16x2, a),
                                __builtin_bit_cast(f16x2, b), c, false);
}

#define GLOAD_LDS16(gptr, lptr)                                          \
  __builtin_amdgcn_global_load_lds(                                      \
      (__attribute__((address_space(1))) void*)(gptr),                   \
      (__attribute__((address_space(3))) void*)(lptr), 16, 0, 0)

__device__ __forceinline__ f32x4 mfma16(f16x8 a, f16x8 b, f32x4 c) {
  return __builtin_amdgcn_mfma_f32_16x16x32_f16(a, b, c, 0, 0, 0);
}

// ---------------- cast fp32 -> f16, 4 elems/thread ----------------
__global__ __launch_bounds__(256) void k_cvt(const float* __restrict__ in,
                                             unsigned short* __restrict__ out,
                                             long n4) {
  long i = (long)blockIdx.x * 256 + threadIdx.x;
  if (i >= n4) return;
  float4 a = reinterpret_cast<const float4*>(in)[i];
  ushort4 o;
  o.x = f2h(a.x); o.y = f2h(a.y); o.z = f2h(a.z); o.w = f2h(a.w);
  reinterpret_cast<ushort4*>(out)[i] = o;
}

// ---- transpose-cast W[K][Norig] fp32 -> Wt[N][K] f16; PERM = head-group ----
// PERM: out col n' = h*192 + t*64 + d  <->  orig col n = t*512 + h*64 + d
template <bool PERM>
__global__ __launch_bounds__(256) void k_cvt_t(const float* __restrict__ W,
                                               unsigned short* __restrict__ Wt,
                                               int K, int Norig) {
  int i = blockIdx.x * 256 + threadIdx.x;
  if (i >= K * Norig) return;
  int np = i / K, k = i - np * K;
  int n = np;
  if (PERM) {
    int h = np / 192, rem = np - h * 192;
    int t = rem >> 6, d = rem & 63;
    n = t * 512 + h * 64 + d;
  }
  Wt[i] = f2h(W[(size_t)k * Norig + n]);
}

// ---- permute bias: bqp[n'] = b[n] ----
__global__ __launch_bounds__(256) void k_permb(const float* __restrict__ b,
                                               float* __restrict__ bqp) {
  int np = blockIdx.x * 256 + threadIdx.x;
  if (np >= 1536) return;
  int h = np / 192, rem = np - h * 192;
  int t = rem >> 6, d = rem & 63;
  bqp[np] = b[t * 512 + h * 64 + d];
}

// ============ fused qkv-GEMM + attention ============
// Block: BM=256 rows (15 batches, row 255 wasted), BN=192 (one head q|k|v),
// BK=64, KT=8, 1024 threads = 16 waves (4M x 4N), per-wave 64x48 (4x3 frags).
// LDS: dbuf (A 256x64 + B 192x64) f16 = 112 KB, linear, T2 swizzle via
// pre-swizzled global source + swizzled ds_read. 1 barrier per K-tile.
#define FB_BUF 28672  // shorts per staging buffer: A 16384 + B 12288

__global__ __launch_bounds__(1024) void k_fused(
    const unsigned short* __restrict__ A,   // xb  [139264][512] f16
    const unsigned short* __restrict__ Bt,  // wqt'[1536][512] f16
    const float* __restrict__ bqp,          // permuted bias [1536]
    const float* __restrict__ outer,        // [8][17][17]
    const float* __restrict__ alpha_p,      // [1]
    unsigned short* __restrict__ ao) {      // [139264][512] f16
  __shared__ __align__(16) unsigned short smem[2 * FB_BUF];
  __shared__ float s_attn[16][17][18];
  __shared__ float s_inv[16][17];

  const int tid = threadIdx.x;
  const int w = tid >> 6, lane = tid & 63;
  const int wm = w >> 2, wn = w & 3;
  const int lr = lane & 15, lk = lane >> 4;

  // bijective XCD swizzle (grid = 547*8)
  const int bid = (blockIdx.x & 7) * ((int)gridDim.x >> 3) + (blockIdx.x >> 3);
  const int mt = bid >> 3, h = bid & 7;
  const int batch0 = mt * 15;
  const int brow = batch0 * 17;
  const int bcol = h * 192;

  const int srowl = lane >> 3;                 // row within 8-row slab
  const int scol = ((lane & 7) ^ srowl) << 3;  // pre-swizzled granule (f16)

  f32x4 acc[4][3];
#pragma unroll
  for (int m = 0; m < 4; m++)
#pragma unroll
    for (int n = 0; n < 3; n++) acc[m][n] = f32x4{0.f, 0.f, 0.f, 0.f};

  // stage K-tile t into buffer buf: 56 slabs (A:32, B:24), 1 gload each
  auto STAGE = [&](int t, int buf) {
    unsigned short* dstbase = smem + buf * FB_BUF;
    for (int s = w; s < 56; s += 16) {
      unsigned short* dst = dstbase + s * 512;  // wave-uniform
      const unsigned short* src;
      if (s < 32) {
        int gr = brow + s * 8 + srowl;
        if (gr > 139263) gr = 139263;  // clamp last tile
        src = A + (size_t)gr * 512 + t * 64 + scol;
      } else {
        int r = (s - 32) * 8 + srowl;
        src = Bt + (size_t)(bcol + r) * 512 + t * 64 + scol;
      }
      GLOAD_LDS16(src, dst);
    }
  };

  STAGE(0, 0);
  asm volatile("s_waitcnt vmcnt(0)" ::: "memory");
  __builtin_amdgcn_s_barrier();

  for (int t = 0; t < 8; ++t) {
    const int ub = (t & 1) * FB_BUF;
    if (t < 7) STAGE(t + 1, (t + 1) & 1);
    const unsigned short* sa = smem + ub + (wm * 64 + lr) * 64;
    const unsigned short* sb = smem + ub + 16384 + (wn * 48 + lr) * 64;
#pragma unroll
    for (int kk = 0; kk < 2; ++kk) {
      const int gx = (((kk << 2) + lk) ^ (lr & 7)) << 3;
      f16x8 av0 = *(const f16x8*)(sa + gx);
      f16x8 av1 = *(const f16x8*)(sa + 1024 + gx);
      f16x8 av2 = *(const f16x8*)(sa + 2048 + gx);
      f16x8 av3 = *(const f16x8*)(sa + 3072 + gx);
      f16x8 bv0 = *(const f16x8*)(sb + gx);
      f16x8 bv1 = *(const f16x8*)(sb + 1024 + gx);
      f16x8 bv2 = *(const f16x8*)(sb + 2048 + gx);
      acc[0][0] = mfma16(av0, bv0, acc[0][0]);
      acc[0][1] = mfma16(av0, bv1, acc[0][1]);
      acc[0][2] = mfma16(av0, bv2, acc[0][2]);
      acc[1][0] = mfma16(av1, bv0, acc[1][0]);
      acc[1][1] = mfma16(av1, bv1, acc[1][1]);
      acc[1][2] = mfma16(av1, bv2, acc[1][2]);
      acc[2][0] = mfma16(av2, bv0, acc[2][0]);
      acc[2][1] = mfma16(av2, bv1, acc[2][1]);
      acc[2][2] = mfma16(av2, bv2, acc[2][2]);
      acc[3][0] = mfma16(av3, bv0, acc[3][0]);
      acc[3][1] = mfma16(av3, bv1, acc[3][1]);
      acc[3][2] = mfma16(av3, bv2, acc[3][2]);
    }
    asm volatile("s_waitcnt vmcnt(0)" ::: "memory");
    __builtin_amdgcn_s_barrier();
  }

  // ---- epilogue 1: acc(+bias) -> smem as f16 [256 rows][stride 200] ----
  {
    const int er0 = wm * 64 + (lane >> 4) * 4;
    const int ec0 = wn * 48 + lr;
    float bvv[3];
#pragma unroll
    for (int nf = 0; nf < 3; ++nf) bvv[nf] = bqp[bcol + ec0 + nf * 16];
#pragma unroll
    for (int mf = 0; mf < 4; ++mf)
#pragma unroll
      for (int nf = 0; nf < 3; ++nf)
#pragma unroll
        for (int rr = 0; rr < 4; ++rr)
          smem[(er0 + mf * 16 + rr) * 200 + ec0 + nf * 16] =
              f2h(acc[mf][nf][rr] + bvv[nf]);
  }
  __syncthreads();

  // ---- epilogue 2: attention, one wave per batch ----
  const int nb = min(15, 8192 - batch0);
  if (w < nb) {
    const float alpha = alpha_p[0];
    const unsigned short* sA0 = smem + (w * 17) * 200;
    for (int p = lane; p < 289; p += 64) {
      const int r = p / 17, m = p - r * 17;
      const uint4* qr = (const uint4*)(sA0 + r * 200);
      const uint4* km = (const uint4*)(sA0 + m * 200 + 64);
      float s = 0.f;
#pragma unroll
      for (int c = 0; c < 8; ++c) {
        uint4 qa = qr[c], ka = km[c];
        s = fdot2u(qa.x, ka.x, s);
        s = fdot2u(qa.y, ka.y, s);
        s = fdot2u(qa.z, ka.z, s);
        s = fdot2u(qa.w, ka.w, s);
      }
      s_attn[w][r][m] = (s + alpha * outer[h * 289 + p]) * 0.125f;
    }
    __builtin_amdgcn_wave_barrier();
    asm volatile("" ::: "memory");

    if (lane < 17) {
      float mx = -1e30f;
#pragma unroll
      for (int m = 0; m < 17; m++) mx = fmaxf(mx, s_attn[w][lane][m]);
      float s = 0.f;
#pragma unroll
      for (int m = 0; m < 17; m++) {
        float e = __expf(s_attn[w][lane][m] - mx);
        s_attn[w][lane][m] = e;
        s += e;
      }
      s_inv[w][lane] = 1.f / s;
    }
    __builtin_amdgcn_wave_barrier();
    asm volatile("" ::: "memory");

    float vr[17];
#pragma unroll
    for (int m = 0; m < 17; m++)
      vr[m] = h2f(smem[(w * 17 + m) * 200 + 128 + lane]);
    const size_t obase = ((size_t)(batch0 + w) * 17) * 512 + h * 64 + lane;
#pragma unroll 1
    for (int r = 0; r < 17; ++r) {
      float o = 0.f;
#pragma unroll
      for (int m = 0; m < 17; m++) o += s_attn[w][r][m] * vr[m];
      ao[obase + (size_t)r * 512] = f2h(o * s_inv[w][r]);
    }
  }
}

// ============ 256x256 8-phase GEMM (proj), unchanged from R3 ============
#define MFMA_QUAD(M0, N0)                                                  \
  __builtin_amdgcn_s_setprio(1);                                           \
  _Pragma("unroll") for (int m_ = 0; m_ < 4; m_++) {                       \
    _Pragma("unroll") for (int n_ = 0; n_ < 2; n_++) {                     \
      acc[(M0) + m_][(N0) + n_] =                                          \
          mfma16(a[(M0) + m_][0], b[(N0) + n_][0], acc[(M0) + m_][(N0) + n_]); \
      acc[(M0) + m_][(N0) + n_] =                                          \
          mfma16(a[(M0) + m_][1], b[(N0) + n_][1], acc[(M0) + m_][(N0) + n_]); \
    }                                                                      \
  }                                                                        \
  __builtin_amdgcn_s_setprio(0);

#define READ_A_HALF(MH)                                                    \
  _Pragma("unroll") for (int m_ = 0; m_ < 4; m_++) {                       \
    a[(MH)*4 + m_][0] =                                                    \
        *(const f16x8*)(ldsA + ub + ((MH)*4 + m_) * 1024 + gx0);           \
    a[(MH)*4 + m_][1] =                                                    \
        *(const f16x8*)(ldsA + ub + ((MH)*4 + m_) * 1024 + gx1);           \
  }
#define READ_B_HALF(NH)                                                    \
  _Pragma("unroll") for (int n_ = 0; n_ < 2; n_++) {                       \
    b[(NH)*2 + n_][0] =                                                    \
        *(const f16x8*)(ldsB + ub + ((NH)*2 + n_) * 1024 + gx0);           \
    b[(NH)*2 + n_][1] =                                                    \
        *(const f16x8*)(ldsB + ub + ((NH)*2 + n_) * 1024 + gx1);           \
  }

template <int KT, bool F16OUT>
__global__ __launch_bounds__(512, 2) void k_gemm256(
    const unsigned short* __restrict__ A, const unsigned short* __restrict__ Bt,
    const float* __restrict__ bias, void* __restrict__ Cout, int M, int N,
    int K) {
  __shared__ __align__(16) unsigned short lds[2][2][256 * 64];

  const int tid = threadIdx.x;
  const int w = tid >> 6, lane = tid & 63;
  const int wm = w >> 2, wn = w & 3;
  const int lr = lane & 15, lk = lane >> 4;

  const int bid = (blockIdx.x & 7) * ((int)gridDim.x >> 3) + (blockIdx.x >> 3);
  const int nbn = N >> 8;
  const int brow = (bid / nbn) << 8;
  const int bcol = (bid % nbn) << 8;

  const int srow = lane >> 3;
  const int scol = (((lane & 7) ^ srow) << 3);
  const unsigned short* pA = A + (size_t)(brow + (w << 3) + srow) * K + scol;
  const unsigned short* pB = Bt + (size_t)(bcol + (w << 3) + srow) * K + scol;

  auto STAGE = [&](int hh) {
    const int uu = hh >> 2, s = hh & 3;
    const int isB = s >> 1, half = s & 1;
    const unsigned short* src =
        (isB ? pB : pA) + (size_t)(half * 128) * K + uu * 64;
    unsigned short* dst = &lds[uu & 1][isB][(half * 128 + (w << 3)) * 64];
    GLOAD_LDS16(src, dst);
    GLOAD_LDS16(src + (size_t)64 * K, dst + 64 * 64);
  };

  const int gx0 = ((lk) ^ (lr & 7)) << 3;
  const int gx1 = ((4 + lk) ^ (lr & 7)) << 3;
  const unsigned short* ldsA = &lds[0][0][(wm * 128 + lr) * 64];
  const unsigned short* ldsB = &lds[0][1][(wn * 64 + lr) * 64];

  f32x4 acc[8][4];
#pragma unroll
  for (int m = 0; m < 8; m++)
#pragma unroll
    for (int n = 0; n < 4; n++) acc[m][n] = f32x4{0.f, 0.f, 0.f, 0.f};

#pragma unroll
  for (int hh = 0; hh < 7; ++hh) STAGE(hh);
  asm volatile("s_waitcnt vmcnt(6)" ::: "memory");
  __builtin_amdgcn_s_barrier();

  f16x8 a[8][2], b[4][2];
  for (int u = 0; u < KT; ++u) {
    const int ub = (u & 1) * 32768;
    const int hbase = 4 * u + 7;
    READ_A_HALF(0)
    READ_B_HALF(0)
    if (hbase < 4 * KT) STAGE(hbase);
    __builtin_amdgcn_s_barrier();
    asm volatile("s_waitcnt lgkmcnt(0)" ::: "memory");
    __builtin_amdgcn_sched_barrier(0);
    MFMA_QUAD(0, 0)
    __builtin_amdgcn_s_barrier();
    READ_A_HALF(1)
    READ_B_HALF(1)
    if (hbase + 1 < 4 * KT) STAGE(hbase + 1);
    __builtin_amdgcn_s_barrier();
    asm volatile("s_waitcnt lgkmcnt(0)" ::: "memory");
    __builtin_amdgcn_sched_barrier(0);
    MFMA_QUAD(0, 2)
    __builtin_amdgcn_s_barrier();
    if (hbase + 2 < 4 * KT) STAGE(hbase + 2);
    __builtin_amdgcn_s_barrier();
    MFMA_QUAD(4, 2)
    __builtin_amdgcn_s_barrier();
    if (hbase + 3 < 4 * KT) STAGE(hbase + 3);
    if (u + 2 < KT) {
      asm volatile("s_waitcnt vmcnt(6)" ::: "memory");
    } else if (u + 2 == KT) {
      asm volatile("s_waitcnt vmcnt(0)" ::: "memory");
    }
    __builtin_amdgcn_s_barrier();
    MFMA_QUAD(4, 0)
    __builtin_amdgcn_s_barrier();
  }

  const int orow = brow + wm * 128 + (lane >> 4) * 4;
  const int ocol0 = bcol + wn * 64 + lr;
#pragma unroll
  for (int n = 0; n < 4; n++) {
    const int col = ocol0 + n * 16;
    const float bv = bias[col];
#pragma unroll
    for (int m = 0; m < 8; m++) {
      const int row = orow + m * 16;
#pragma unroll
      for (int r = 0; r < 4; r++) {
        float v = acc[m][n][r] + bv;
        if (F16OUT)
          ((unsigned short*)Cout)[(size_t)(row + r) * N + col] = f2h(v);
        else
          ((float*)Cout)[(size_t)(row + r) * N + col] = v;
      }
    }
  }
}

// ---------------- launch ----------------
extern "C" void kernel_launch(void* const* d_in, const int* in_sizes, int n_in,
                              void* d_out, int out_size, void* d_ws,
                              size_t ws_size, hipStream_t stream) {
  const float* x      = (const float*)d_in[0];
  const float* W_qkv  = (const float*)d_in[1];
  const float* b_qkv  = (const float*)d_in[2];
  const float* outer  = (const float*)d_in[3];
  const float* alpha  = (const float*)d_in[4];
  const float* W_proj = (const float*)d_in[5];
  const float* b_proj = (const float*)d_in[6];

  char* ws = (char*)d_ws;
  unsigned short* xb  = (unsigned short*)(ws);              // 142,606,336 B
  unsigned short* ao  = (unsigned short*)(ws + 142606336);  // 142,606,336 B
  unsigned short* wqt = (unsigned short*)(ws + 285212672);  // 1,572,864 B
  unsigned short* wpt = (unsigned short*)(ws + 286785536);  // 524,288 B
  float*          bqp = (float*)(ws + 287309824);           // 6,144 B

  k_cvt<<<dim3(69632), dim3(256), 0, stream>>>(x, xb, 17825792L);
  k_cvt_t<true><<<dim3(3072), dim3(256), 0, stream>>>(W_qkv, wqt, 512, 1536);
  k_cvt_t<false><<<dim3(1024), dim3(256), 0, stream>>>(W_proj, wpt, 512, 512);
  k_permb<<<dim3(6), dim3(256), 0, stream>>>(b_qkv, bqp);

  // fused qkv-GEMM + attention: 547 row-tiles (15 batches each) x 8 heads
  k_fused<<<dim3(4376), dim3(1024), 0, stream>>>(xb, wqt, bqp, outer, alpha, ao);

  // proj GEMM: 544 x 2 = 1088 blocks, fp32 out
  k_gemm256<8, false><<<dim3(1088), dim3(512), 0, stream>>>(
      ao, wpt, b_proj, (float*)d_out, 139264, 512, 512);
}

// Round 5
// 594.009 us; speedup vs baseline: 1.4600x; 1.2230x over previous
//
#include <hip/hip_runtime.h>
#include <stdint.h>

// B=8192, N=17, C=512, H=8, HD=64 — f16 pipeline (inputs fp32)
// Fused qkv-GEMM (head-grouped W) + per-batch attention; 2 blocks/CU.

typedef __attribute__((ext_vector_type(4))) float f32x4;
typedef _Float16 f16x8 __attribute__((ext_vector_type(8)));
typedef _Float16 f16x2 __attribute__((ext_vector_type(2)));

__device__ __forceinline__ unsigned short f2h(float f) {
  return __builtin_bit_cast(unsigned short, (_Float16)f);
}
__device__ __forceinline__ float h2f(unsigned short h) {
  return (float)__builtin_bit_cast(_Float16, h);
}
__device__ __forceinline__ float fdot2u(uint32_t a, uint32_t b, float c) {
  return __builtin_amdgcn_fdot2(__builtin_bit_cast(f16x2, a),
                                __builtin_bit_cast(f16x2, b), c, false);
}

#define GLOAD_LDS16(gptr, lptr)                                          \
  __builtin_amdgcn_global_load_lds(                                      \
      (__attribute__((address_space(1))) void*)(gptr),                   \
      (__attribute__((address_space(3))) void*)(lptr), 16, 0, 0)

__device__ __forceinline__ f32x4 mfma16(f16x8 a, f16x8 b, f32x4 c) {
  return __builtin_amdgcn_mfma_f32_16x16x32_f16(a, b, c, 0, 0, 0);
}

// ---------------- cast fp32 -> f16, 4 elems/thread ----------------
__global__ __launch_bounds__(256) void k_cvt(const float* __restrict__ in,
                                             unsigned short* __restrict__ out,
                                             long n4) {
  long i = (long)blockIdx.x * 256 + threadIdx.x;
  if (i >= n4) return;
  float4 a = reinterpret_cast<const float4*>(in)[i];
  ushort4 o;
  o.x = f2h(a.x); o.y = f2h(a.y); o.z = f2h(a.z); o.w = f2h(a.w);
  reinterpret_cast<ushort4*>(out)[i] = o;
}

// ---- transpose-cast W[K][Norig] fp32 -> Wt[N][K] f16; PERM = head-group ----
// PERM: out col n' = h*192 + t*64 + d  <->  orig col n = t*512 + h*64 + d
template <bool PERM>
__global__ __launch_bounds__(256) void k_cvt_t(const float* __restrict__ W,
                                               unsigned short* __restrict__ Wt,
                                               int K, int Norig) {
  int i = blockIdx.x * 256 + threadIdx.x;
  if (i >= K * Norig) return;
  int np = i / K, k = i - np * K;
  int n = np;
  if (PERM) {
    int h = np / 192, rem = np - h * 192;
    int t = rem >> 6, d = rem & 63;
    n = t * 512 + h * 64 + d;
  }
  Wt[i] = f2h(W[(size_t)k * Norig + n]);
}

// ---- permute bias: bqp[n'] = b[n] ----
__global__ __launch_bounds__(256) void k_permb(const float* __restrict__ b,
                                               float* __restrict__ bqp) {
  int np = blockIdx.x * 256 + threadIdx.x;
  if (np >= 1536) return;
  int h = np / 192, rem = np - h * 192;
  int t = rem >> 6, d = rem & 63;
  bqp[np] = b[t * 512 + h * 64 + d];
}

// ============ fused qkv-GEMM + attention, 2 blocks/CU ============
// BM=128 rows (7 batches, rows 119-127 clamped/wasted), BN=192 (one head),
// BK=64, KT=8, 512 threads = 8 waves (2M x 4N), per-wave 64x48 (4x3 frags).
// Staging LDS: dbuf x (A 128x64 + B 192x64) f16 = 81,920 B exactly ->
// 2 blocks/CU. Epilogue scratch overlays the dead staging buffers.
#define FBUF 20480  // shorts per buffer: A 8192 + B 12288

__global__ __launch_bounds__(512, 4) void k_fused(
    const unsigned short* __restrict__ A,   // xb  [139264][512] f16
    const unsigned short* __restrict__ Bt,  // wqt'[1536][512] f16
    const float* __restrict__ bqp,          // permuted bias [1536]
    const float* __restrict__ outer,        // [8][17][17]
    const float* __restrict__ alpha_p,      // [1]
    unsigned short* __restrict__ ao) {      // [139264][512] f16
  __shared__ __align__(16) unsigned short smem[2 * FBUF];  // 81,920 B

  const int tid = threadIdx.x;
  const int w = tid >> 6, lane = tid & 63;
  const int wm = w >> 2, wn = w & 3;
  const int lr = lane & 15, lk = lane >> 4;

  // bijective XCD swizzle (grid = 1171*8); h inner => 8 blocks sharing an
  // A-panel stay in one XCD chunk.
  const int bid = (blockIdx.x & 7) * ((int)gridDim.x >> 3) + (blockIdx.x >> 3);
  const int mt = bid >> 3, h = bid & 7;
  const int batch0 = mt * 7;
  const int brow = batch0 * 17;
  const int bcol = h * 192;

  const int srowl = lane >> 3;                 // row within 8-row slab
  const int scol = ((lane & 7) ^ srowl) << 3;  // pre-swizzled granule (f16)

  f32x4 acc[4][3];
#pragma unroll
  for (int m = 0; m < 4; m++)
#pragma unroll
    for (int n = 0; n < 3; n++) acc[m][n] = f32x4{0.f, 0.f, 0.f, 0.f};

  // stage K-tile t: 40 slabs (A:16, B:24), 5 gloads per wave
  auto STAGE = [&](int t, int buf) {
    unsigned short* dstbase = smem + buf * FBUF;
#pragma unroll
    for (int s5 = 0; s5 < 5; ++s5) {
      const int s = w + s5 * 8;
      unsigned short* dst = dstbase + s * 512;  // wave-uniform
      const unsigned short* src;
      if (s < 16) {
        int gr = brow + s * 8 + srowl;
        if (gr > 139263) gr = 139263;  // clamp last row-tile
        src = A + (size_t)gr * 512 + t * 64 + scol;
      } else {
        int r = (s - 16) * 8 + srowl;
        src = Bt + (size_t)(bcol + r) * 512 + t * 64 + scol;
      }
      GLOAD_LDS16(src, dst);
    }
  };

  STAGE(0, 0);
  asm volatile("s_waitcnt vmcnt(0)" ::: "memory");
  __builtin_amdgcn_s_barrier();

  for (int t = 0; t < 8; ++t) {
    const int ub = (t & 1) * FBUF;
    if (t < 7) STAGE(t + 1, (t + 1) & 1);
    const unsigned short* sa = smem + ub + (wm * 64 + lr) * 64;
    const unsigned short* sb = smem + ub + 8192 + (wn * 48 + lr) * 64;
#pragma unroll
    for (int kk = 0; kk < 2; ++kk) {
      const int gx = (((kk << 2) + lk) ^ (lr & 7)) << 3;
      f16x8 av0 = *(const f16x8*)(sa + gx);
      f16x8 av1 = *(const f16x8*)(sa + 1024 + gx);
      f16x8 av2 = *(const f16x8*)(sa + 2048 + gx);
      f16x8 av3 = *(const f16x8*)(sa + 3072 + gx);
      f16x8 bv0 = *(const f16x8*)(sb + gx);
      f16x8 bv1 = *(const f16x8*)(sb + 1024 + gx);
      f16x8 bv2 = *(const f16x8*)(sb + 2048 + gx);
      acc[0][0] = mfma16(av0, bv0, acc[0][0]);
      acc[0][1] = mfma16(av0, bv1, acc[0][1]);
      acc[0][2] = mfma16(av0, bv2, acc[0][2]);
      acc[1][0] = mfma16(av1, bv0, acc[1][0]);
      acc[1][1] = mfma16(av1, bv1, acc[1][1]);
      acc[1][2] = mfma16(av1, bv2, acc[1][2]);
      acc[2][0] = mfma16(av2, bv0, acc[2][0]);
      acc[2][1] = mfma16(av2, bv1, acc[2][1]);
      acc[2][2] = mfma16(av2, bv2, acc[2][2]);
      acc[3][0] = mfma16(av3, bv0, acc[3][0]);
      acc[3][1] = mfma16(av3, bv1, acc[3][1]);
      acc[3][2] = mfma16(av3, bv2, acc[3][2]);
    }
    asm volatile("s_waitcnt vmcnt(0)" ::: "memory");
    __builtin_amdgcn_s_barrier();
  }

  // ---- epilogue overlay on dead staging memory ----
  // rows: [128][200] f16 at shorts 0..25599; s_attn [7][17][18] f32 at 25600;
  // s_inv [7][17] f32 after that. Total 60,244 B <= 81,920 B.
  float* s_attn = (float*)(smem + 25600);
  float* s_inv = (float*)(smem + 25600 + 2 * (7 * 17 * 18));

  // epilogue 1: acc(+bias) -> smem rows as f16
  {
    const int er0 = wm * 64 + (lane >> 4) * 4;
    const int ec0 = wn * 48 + lr;
    float bvv[3];
#pragma unroll
    for (int nf = 0; nf < 3; ++nf) bvv[nf] = bqp[bcol + ec0 + nf * 16];
#pragma unroll
    for (int mf = 0; mf < 4; ++mf)
#pragma unroll
      for (int nf = 0; nf < 3; ++nf)
#pragma unroll
        for (int rr = 0; rr < 4; ++rr)
          smem[(er0 + mf * 16 + rr) * 200 + ec0 + nf * 16] =
              f2h(acc[mf][nf][rr] + bvv[nf]);
  }
  __syncthreads();

  // epilogue 2: attention, one wave per batch (waves 0..nb-1)
  const int nb = min(7, 8192 - batch0);
  if (w < nb) {
    const float alpha = alpha_p[0];
    const unsigned short* sA0 = smem + (w * 17) * 200;
    for (int p = lane; p < 289; p += 64) {
      const int r = p / 17, m = p - r * 17;
      const uint4* qr = (const uint4*)(sA0 + r * 200);
      const uint4* km = (const uint4*)(sA0 + m * 200 + 64);
      float s = 0.f;
#pragma unroll
      for (int c = 0; c < 8; ++c) {
        uint4 qa = qr[c], ka = km[c];
        s = fdot2u(qa.x, ka.x, s);
        s = fdot2u(qa.y, ka.y, s);
        s = fdot2u(qa.z, ka.z, s);
        s = fdot2u(qa.w, ka.w, s);
      }
      s_attn[(w * 17 + r) * 18 + m] = (s + alpha * outer[h * 289 + p]) * 0.125f;
    }
    __builtin_amdgcn_wave_barrier();
    asm volatile("" ::: "memory");

    if (lane < 17) {
      float mx = -1e30f;
#pragma unroll
      for (int m = 0; m < 17; m++)
        mx = fmaxf(mx, s_attn[(w * 17 + lane) * 18 + m]);
      float s = 0.f;
#pragma unroll
      for (int m = 0; m < 17; m++) {
        float e = __expf(s_attn[(w * 17 + lane) * 18 + m] - mx);
        s_attn[(w * 17 + lane) * 18 + m] = e;
        s += e;
      }
      s_inv[w * 17 + lane] = 1.f / s;
    }
    __builtin_amdgcn_wave_barrier();
    asm volatile("" ::: "memory");

    float vr[17];
#pragma unroll
    for (int m = 0; m < 17; m++)
      vr[m] = h2f(smem[(w * 17 + m) * 200 + 128 + lane]);
    const size_t obase = ((size_t)(batch0 + w) * 17) * 512 + h * 64 + lane;
#pragma unroll 1
    for (int r = 0; r < 17; ++r) {
      float o = 0.f;
#pragma unroll
      for (int m = 0; m < 17; m++) o += s_attn[(w * 17 + r) * 18 + m] * vr[m];
      ao[obase + (size_t)r * 512] = f2h(o * s_inv[w * 17 + r]);
    }
  }
}

// ============ proj GEMM: 128x128 tile, 2 blocks/CU ============
// 512 thr = 8 waves (2M x 4N), per-wave 64x32 (4x2 frags), BK=64, KT=8.
// LDS: dbuf x (A 128x64 + B 128x64) f16 = 65,536 B -> 2 blocks/CU.
#define PBUF 16384  // shorts per buffer

__global__ __launch_bounds__(512, 4) void k_proj(
    const unsigned short* __restrict__ A,   // ao [139264][512] f16
    const unsigned short* __restrict__ Bt,  // wpt [512][512] f16
    const float* __restrict__ bias,         // [512]
    float* __restrict__ C) {                // [139264][512] fp32
  __shared__ __align__(16) unsigned short smem[2 * PBUF];

  const int tid = threadIdx.x;
  const int w = tid >> 6, lane = tid & 63;
  const int wm = w >> 2, wn = w & 3;
  const int lr = lane & 15, lk = lane >> 4;

  const int bid = (blockIdx.x & 7) * ((int)gridDim.x >> 3) + (blockIdx.x >> 3);
  const int brow = (bid >> 2) << 7;   // 1088 row tiles
  const int bcol = (bid & 3) << 7;    // 4 col tiles

  const int srowl = lane >> 3;
  const int scol = ((lane & 7) ^ srowl) << 3;

  f32x4 acc[4][2];
#pragma unroll
  for (int m = 0; m < 4; m++)
#pragma unroll
    for (int n = 0; n < 2; n++) acc[m][n] = f32x4{0.f, 0.f, 0.f, 0.f};

  auto STAGE = [&](int t, int buf) {
    unsigned short* dstbase = smem + buf * PBUF;
#pragma unroll
    for (int s4 = 0; s4 < 4; ++s4) {
      const int s = w + s4 * 8;
      unsigned short* dst = dstbase + s * 512;
      const unsigned short* src =
          (s < 16) ? A + (size_t)(brow + s * 8 + srowl) * 512 + t * 64 + scol
                   : Bt + (size_t)(bcol + (s - 16) * 8 + srowl) * 512 + t * 64 + scol;
      GLOAD_LDS16(src, dst);
    }
  };

  STAGE(0, 0);
  asm volatile("s_waitcnt vmcnt(0)" ::: "memory");
  __builtin_amdgcn_s_barrier();

  for (int t = 0; t < 8; ++t) {
    const int ub = (t & 1) * PBUF;
    if (t < 7) STAGE(t + 1, (t + 1) & 1);
    const unsigned short* sa = smem + ub + (wm * 64 + lr) * 64;
    const unsigned short* sb = smem + ub + 8192 + (wn * 32 + lr) * 64;
#pragma unroll
    for (int kk = 0; kk < 2; ++kk) {
      const int gx = (((kk << 2) + lk) ^ (lr & 7)) << 3;
      f16x8 av0 = *(const f16x8*)(sa + gx);
      f16x8 av1 = *(const f16x8*)(sa + 1024 + gx);
      f16x8 av2 = *(const f16x8*)(sa + 2048 + gx);
      f16x8 av3 = *(const f16x8*)(sa + 3072 + gx);
      f16x8 bv0 = *(const f16x8*)(sb + gx);
      f16x8 bv1 = *(const f16x8*)(sb + 1024 + gx);
      acc[0][0] = mfma16(av0, bv0, acc[0][0]);
      acc[0][1] = mfma16(av0, bv1, acc[0][1]);
      acc[1][0] = mfma16(av1, bv0, acc[1][0]);
      acc[1][1] = mfma16(av1, bv1, acc[1][1]);
      acc[2][0] = mfma16(av2, bv0, acc[2][0]);
      acc[2][1] = mfma16(av2, bv1, acc[2][1]);
      acc[3][0] = mfma16(av3, bv0, acc[3][0]);
      acc[3][1] = mfma16(av3, bv1, acc[3][1]);
    }
    asm volatile("s_waitcnt vmcnt(0)" ::: "memory");
    __builtin_amdgcn_s_barrier();
  }

  const int orow = brow + wm * 64 + (lane >> 4) * 4;
  const int ocol0 = bcol + wn * 32 + lr;
#pragma unroll
  for (int n = 0; n < 2; n++) {
    const int col = ocol0 + n * 16;
    const float bv = bias[col];
#pragma unroll
    for (int m = 0; m < 4; m++) {
      const int row = orow + m * 16;
#pragma unroll
      for (int r = 0; r < 4; r++)
        C[(size_t)(row + r) * 512 + col] = acc[m][n][r] + bv;
    }
  }
}

// ---------------- launch ----------------
extern "C" void kernel_launch(void* const* d_in, const int* in_sizes, int n_in,
                              void* d_out, int out_size, void* d_ws,
                              size_t ws_size, hipStream_t stream) {
  const float* x      = (const float*)d_in[0];
  const float* W_qkv  = (const float*)d_in[1];
  const float* b_qkv  = (const float*)d_in[2];
  const float* outer  = (const float*)d_in[3];
  const float* alpha  = (const float*)d_in[4];
  const float* W_proj = (const float*)d_in[5];
  const float* b_proj = (const float*)d_in[6];

  char* ws = (char*)d_ws;
  unsigned short* xb  = (unsigned short*)(ws);              // 142,606,336 B
  unsigned short* ao  = (unsigned short*)(ws + 142606336);  // 142,606,336 B
  unsigned short* wqt = (unsigned short*)(ws + 285212672);  // 1,572,864 B
  unsigned short* wpt = (unsigned short*)(ws + 286785536);  // 524,288 B
  float*          bqp = (float*)(ws + 287309824);           // 6,144 B

  k_cvt<<<dim3(69632), dim3(256), 0, stream>>>(x, xb, 17825792L);
  k_cvt_t<true><<<dim3(3072), dim3(256), 0, stream>>>(W_qkv, wqt, 512, 1536);
  k_cvt_t<false><<<dim3(1024), dim3(256), 0, stream>>>(W_proj, wpt, 512, 512);
  k_permb<<<dim3(6), dim3(256), 0, stream>>>(b_qkv, bqp);

  // fused qkv-GEMM + attention: 1171 row-tiles (7 batches each) x 8 heads
  k_fused<<<dim3(9368), dim3(512), 0, stream>>>(xb, wqt, bqp, outer, alpha, ao);

  // proj GEMM: 1088 row-tiles x 4 col-tiles
  k_proj<<<dim3(4352), dim3(512), 0, stream>>>(ao, wpt, b_proj, (float*)d_out);
}